// Round 19
// baseline (288.676 us; speedup 1.0000x reference)
//
#include <hip/hip_runtime.h>

constexpr int N    = 8192;
constexpr int NPG  = 512;   // nodes per graph
constexpr int NG   = 16;
constexpr int KNN  = 80;
constexpr int F0   = 6;
constexpr int HID  = 128;
constexpr int H6   = 768;
constexpr int RPB  = 16;    // rows per combine block
constexpr int BPGR = NPG / RPB;  // combine blocks per graph = 32
constexpr size_t SPLIT_STRIDE = (size_t)NG * HID * NPG;   // elems per split plane

typedef _Float16 half8 __attribute__((ext_vector_type(8)));
typedef float    f32x4 __attribute__((ext_vector_type(4)));

__device__ __forceinline__ float leaky(float v) { return v > 0.0f ? v : 0.01f * v; }

__device__ __forceinline__ int lanes_below(unsigned long long m) {
    return __builtin_amdgcn_mbcnt_hi((unsigned)(m >> 32),
           __builtin_amdgcn_mbcnt_lo((unsigned)m, 0));
}

// wave-sum of a per-lane count in [0,8] via 4 ballots (result uniform)
__device__ __forceinline__ int wave_count_sum(int c) {
    int total = 0;
    #pragma unroll
    for (int b = 0; b < 4; b++)
        total += (int)__popcll(__ballot((c >> b) & 1)) << b;
    return total;
}

// ---------------------------------------------------------------------------
// KNN, wave-per-target (see R2 notes). XCD-mapped. Also builds dense fp16
// adjacency A[8192][512] (row zero + 80 scatter ones; verified R5/R6).
// ---------------------------------------------------------------------------
__global__ __launch_bounds__(256) void knn_kernel(const float* __restrict__ x,
                                                  int* __restrict__ nbr,
                                                  _Float16* __restrict__ Aadj) {
    const int bid   = blockIdx.x;
    const int slot  = bid & 7;
    const int idx   = bid >> 3;                 // 0..255
    const int g     = slot + 8 * (idx >> 7);    // graph, 2 per XCD
    const int chunk = idx & 127;                // 128 chunks of 4 targets
    const int tid  = threadIdx.x;
    const int lane = tid & 63;
    const int wv   = tid >> 6;
    const int base = g << 9;
    const int tl   = chunk * 4 + wv;
    const int t    = base + tl;

    __shared__ float px[512], py[512], pz[512], pw[512];
    __shared__ unsigned long long skey[4 * 128];

    {   // zero this wave's adjacency row (512 fp16 = 1KB, 16B per lane)
        const uint4 z = {0u, 0u, 0u, 0u};
        *(uint4*)(Aadj + (size_t)t * 512 + lane * 8) = z;
    }

    for (int j = tid; j < 512; j += 256) {
        const float* row = x + (size_t)(base + j) * F0;
        const float2 ra = *(const float2*)(row);
        const float2 rb = *(const float2*)(row + 2);
        px[j] = ra.x; py[j] = ra.y; pz[j] = rb.x; pw[j] = rb.y;
    }
    __syncthreads();

    const float tx = px[tl], ty = py[tl], tz = pz[tl], tw = pw[tl];
    const float sqt = tx*tx + ty*ty + tz*tz + tw*tw;

    unsigned d2m[8];
    #pragma unroll
    for (int j = 0; j < 8; j++) {
        const int node = j * 64 + lane;
        const float jx = px[node], jy = py[node], jz = pz[node], jw = pw[node];
        const float sqj = jx*jx + jy*jy + jz*jz + jw*jw;
        const float dot = tx*jx + ty*jy + tz*jz + tw*jw;
        const float d2  = sqt + sqj - 2.0f * dot;
        unsigned u = __float_as_uint(d2);
        u = (u & 0x80000000u) ? ~u : (u | 0x80000000u);   // monotonic map
        d2m[j] = (node == tl) ? 0xFFFFFFFFu : u;          // exclude self
    }

    unsigned V = 0;
    for (int b = 31; b >= 0; --b) {
        const unsigned test = V | (1u << b);
        int c = 0;
        #pragma unroll
        for (int j = 0; j < 8; j++) c += (d2m[j] < test) ? 1 : 0;
        if (wave_count_sum(c) < KNN) V = test;
    }

    int c = 0;
    #pragma unroll
    for (int j = 0; j < 8; j++) c += (d2m[j] < V) ? 1 : 0;
    const int n_lt = wave_count_sum(c);
    const int need = KNN - n_lt;

    const int woff = wv * 128;
    int cnt_total = 0, taken = 0;
    #pragma unroll
    for (int j = 0; j < 8; j++) {
        const bool lt = d2m[j] < V;
        const bool eq = d2m[j] == V;
        const unsigned long long meq = __ballot(eq);
        const bool sel = lt || (eq && (taken + lanes_below(meq)) < need);
        taken += (int)__popcll(meq);
        const unsigned long long msel = __ballot(sel);
        if (sel) {
            const int pos = cnt_total + lanes_below(msel);
            skey[woff + pos] = ((unsigned long long)d2m[j] << 32)
                             | (unsigned)(base + j * 64 + lane);
        }
        cnt_total += (int)__popcll(msel);
    }
    for (int i = KNN + lane; i < 128; i += 64) skey[woff + i] = ~0ULL;
    __syncthreads();

    for (int kk = 2; kk <= 128; kk <<= 1) {
        for (int jj = kk >> 1; jj >= 1; jj >>= 1) {
            const int i  = ((lane & ~(jj - 1)) << 1) | (lane & (jj - 1));
            const int ix = i | jj;
            const unsigned long long a = skey[woff + i];
            const unsigned long long b = skey[woff + ix];
            const bool up = ((i & kk) == 0);
            if ((a > b) == up) { skey[woff + i] = b; skey[woff + ix] = a; }
            __syncthreads();
        }
    }

    if (lane < KNN) {
        const int idxn = (int)(unsigned)skey[woff + lane];
        nbr[t * KNN + lane] = idxn;
        Aadj[(size_t)t * 512 + (idxn & 511)] = (_Float16)1.0f;
    }
    if (lane + 64 < KNN) {
        const int idxn = (int)(unsigned)skey[woff + lane + 64];
        nbr[t * KNN + lane + 64] = idxn;
        Aadj[(size_t)t * 512 + (idxn & 511)] = (_Float16)1.0f;
    }
}

// ---------------------------------------------------------------------------
// prop6: 8 lanes per node, 10 neighbors each, shuffle-reduce. XCD-mapped.
// ---------------------------------------------------------------------------
__global__ __launch_bounds__(256) void prop6(const float* __restrict__ hin,
                                             const int* __restrict__ nbr,
                                             float* __restrict__ hout) {
    const int bid   = blockIdx.x;
    const int slot  = bid & 7;
    const int idx   = bid >> 3;                 // 0..31
    const int g     = slot + 8 * (idx >> 4);    // graph
    const int chunk = idx & 15;                 // 16 chunks of 32 nodes
    const int t     = (g << 9) + chunk * 32 + (threadIdx.x >> 3);
    const int sl    = threadIdx.x & 7;
    const int* nb   = nbr + t * KNN + sl * 10;

    float a[F0] = {0.f, 0.f, 0.f, 0.f, 0.f, 0.f};
    #pragma unroll
    for (int j = 0; j < 10; j++) {
        const float* r = hin + (size_t)nb[j] * F0;
        #pragma unroll
        for (int f = 0; f < F0; f++) a[f] += r[f];
    }
    #pragma unroll
    for (int off = 1; off < 8; off <<= 1)
        #pragma unroll
        for (int f = 0; f < F0; f++) a[f] += __shfl_xor(a[f], off);

    if (sl == 0) {
        const float inv = 1.0f / 80.0f;
        float* o = hout + (size_t)t * F0;
        #pragma unroll
        for (int f = 0; f < F0; f++) o[f] = a[f] * inv;
    }
}

// ---------------------------------------------------------------------------
// split_kernel: H f32 [8192][128] -> transposed fp16 2-split
// Bout[split][g][c][n]. Verified R5/R6 (absmax 0.0). 128 blocks x 256 thr.
// ---------------------------------------------------------------------------
__global__ __launch_bounds__(256) void split_kernel(const float* __restrict__ H,
                                                    _Float16* __restrict__ Bout) {
    __shared__ unsigned tt[128][67];
    const int tid = threadIdx.x;
    const int n0  = blockIdx.x * 64;
    const int g   = n0 >> 9;
    const int nl  = n0 & 511;

    #pragma unroll
    for (int q = 0; q < 8; q++) {
        const int i  = tid + q * 256;           // 2048 float4 units
        const int n  = i >> 5;
        const int c4 = (i & 31) * 4;
        const float4 v = *(const float4*)(H + ((size_t)(n0 + n)) * HID + c4);
        const float fr[4] = {v.x, v.y, v.z, v.w};
        #pragma unroll
        for (int e = 0; e < 4; e++) {
            const float f = fr[e];
            const _Float16 h1 = (_Float16)f;
            const _Float16 h2 = (_Float16)(f - (float)h1);
            tt[c4 + e][n] = ((unsigned)__builtin_bit_cast(unsigned short, h2) << 16)
                          |  (unsigned)__builtin_bit_cast(unsigned short, h1);
        }
    }
    __syncthreads();

    const int c  = tid >> 1;
    const int jh = tid & 1;
    _Float16 o1[32], o2[32];
    #pragma unroll
    for (int s = 0; s < 32; s++) {
        const unsigned u = tt[c][jh * 32 + s];
        o1[s] = __builtin_bit_cast(_Float16, (unsigned short)(u & 0xFFFFu));
        o2[s] = __builtin_bit_cast(_Float16, (unsigned short)(u >> 16));
    }
    _Float16* d1 = Bout + ((size_t)g * HID + c) * NPG + nl + jh * 32;
    _Float16* d2 = d1 + SPLIT_STRIDE;
    #pragma unroll
    for (int q = 0; q < 4; q++) {
        *(uint4*)(d1 + q * 8) = *(const uint4*)&o1[q * 8];
        *(uint4*)(d2 + q * 8) = *(const uint4*)&o2[q * 8];
    }
}

// ---------------------------------------------------------------------------
// hop3: Y = (1/80)*A@(B1+B2) via MFMA 16x16x32 f16, occupancy-fixed.
// Block = (graph, 16-row tile, 64-col half), 128 thr = 2 waves = 2 k-halves.
// Per wave: acc[4] (4 col-tiles, shared A-frag) -> 4 indep MFMA chains; NO
// barriers in K-loop; 2-wave k-reduce in 4.4KB LDS. Grid 1024 (4+ blk/CU).
// Frag/layout math verified in R5/R6 (passed absmax 0.0).
// ---------------------------------------------------------------------------
template<bool EMIT>
__global__ __launch_bounds__(128) void hop3_kernel(const _Float16* __restrict__ A,
                                                   const _Float16* __restrict__ Bin,
                                                   float* __restrict__ Y,
                                                   _Float16* __restrict__ Bout) {
    __shared__ float Cs[16][68];

    const int bid  = blockIdx.x;                 // 0..1023
    const int slot = bid & 7;
    const int g    = slot + 8 * (bid >> 9);      // graph, 2 per XCD
    const int unit = (bid >> 3) & 63;            // 64 units/graph
    const int rtl  = unit >> 1;                  // row tile 0..31
    const int h    = unit & 1;                   // col half
    const int tid  = threadIdx.x;
    const int lane = tid & 63;
    const int w    = tid >> 6;                   // k-half 0/1
    const int base = g << 9;

    const int arow = base + rtl * 16 + (lane & 15);
    const int kl   = (lane >> 4) * 8;            // 0,8,16,24
    const _Float16* Ap = A + (size_t)arow * 512 + w * 256 + kl;

    const int cloc = lane & 15;
    const _Float16* Bp[4];
    #pragma unroll
    for (int jt = 0; jt < 4; jt++) {
        const int col = h * 64 + jt * 16 + cloc;
        Bp[jt] = Bin + ((size_t)g * HID + col) * NPG + w * 256 + kl;
    }

    f32x4 acc[4];
    #pragma unroll
    for (int jt = 0; jt < 4; jt++) acc[jt] = {0.f, 0.f, 0.f, 0.f};

    #pragma unroll
    for (int ks = 0; ks < 8; ks++) {
        const half8 af = *(const half8*)(Ap + ks * 32);
        #pragma unroll
        for (int jt = 0; jt < 4; jt++) {
            const half8 b0 = *(const half8*)(Bp[jt] + ks * 32);
            const half8 b1 = *(const half8*)(Bp[jt] + SPLIT_STRIDE + ks * 32);
            acc[jt] = __builtin_amdgcn_mfma_f32_16x16x32_f16(af, b0, acc[jt], 0, 0, 0);
            acc[jt] = __builtin_amdgcn_mfma_f32_16x16x32_f16(af, b1, acc[jt], 0, 0, 0);
        }
    }

    // 2-wave k-reduce in LDS (C/D layout: row=(lane>>4)*4+rg, col=jt*16+(lane&15))
    const int rb = (lane >> 4) * 4;
    if (w == 0) {
        #pragma unroll
        for (int jt = 0; jt < 4; jt++)
            #pragma unroll
            for (int rg = 0; rg < 4; rg++)
                Cs[rb + rg][jt * 16 + cloc] = acc[jt][rg];
    }
    __syncthreads();
    if (w == 1) {
        #pragma unroll
        for (int jt = 0; jt < 4; jt++)
            #pragma unroll
            for (int rg = 0; rg < 4; rg++)
                Cs[rb + rg][jt * 16 + cloc] += acc[jt][rg];
    }
    __syncthreads();

    const float inv = 1.0f / 80.0f;
    {   // Y f32 row-major, coalesced: 16 rows x 64 cols, 2 float4/thread
        #pragma unroll
        for (int q = 0; q < 2; q++) {
            const int u  = tid + q * 128;       // 256 float4 units
            const int r  = u >> 4;
            const int c4 = (u & 15) * 4;
            float4 o;
            o.x = Cs[r][c4]     * inv;
            o.y = Cs[r][c4 + 1] * inv;
            o.z = Cs[r][c4 + 2] * inv;
            o.w = Cs[r][c4 + 3] * inv;
            *(float4*)(Y + ((size_t)(base + rtl * 16 + r)) * HID + h * 64 + c4) = o;
        }
    }

    if (EMIT) {  // fp16^T splits of Y: thread = (col 0..63, n-oct 0..1)
        const int cl  = tid >> 1;
        const int nq8 = (tid & 1) * 8;
        _Float16 o1[8], o2[8];
        #pragma unroll
        for (int i = 0; i < 8; i++) {
            const float v = Cs[nq8 + i][cl] * inv;
            o1[i] = (_Float16)v;
            o2[i] = (_Float16)(v - (float)o1[i]);
        }
        _Float16* d1 = Bout + ((size_t)g * HID + h * 64 + cl) * NPG + rtl * 16 + nq8;
        _Float16* d2 = d1 + SPLIT_STRIDE;
        *(uint4*)d1 = *(const uint4*)o1;
        *(uint4*)d2 = *(const uint4*)o2;
    }
}

// ---------------------------------------------------------------------------
// combine6: LDS-tiled GEMM for conv1 (K=6) + fused partial pool. XCD-mapped.
// ---------------------------------------------------------------------------
__global__ __launch_bounds__(256) void combine6(const float* __restrict__ X,
                                                const float* __restrict__ Y1,
                                                const float* __restrict__ Y2,
                                                const float* __restrict__ W,
                                                const float* __restrict__ bias,
                                                float* __restrict__ out,
                                                float* __restrict__ psum,
                                                float* __restrict__ pmax) {
    constexpr int K = F0;
    __shared__ float xs[3][RPB * K];
    const int bid   = blockIdx.x;               // 0..511
    const int slot  = bid & 7;
    const int idx   = bid >> 3;                 // 0..63
    const int g     = slot + 8 * (idx >> 5);
    const int tile  = g * BPGR + (idx & 31);    // canonical tile id
    const int row0  = tile * RPB;
    const int tid   = threadIdx.x;

    for (int i = tid; i < RPB * K; i += 256) xs[0][i] = X [(size_t)row0 * K + i];
    for (int i = tid; i < RPB * K; i += 256) xs[1][i] = Y1[(size_t)row0 * K + i];
    for (int i = tid; i < RPB * K; i += 256) xs[2][i] = Y2[(size_t)row0 * K + i];
    __syncthreads();

    const int c  = tid & 127;
    const int r0 = (tid >> 7) * 8;

    float acc[8];
    #pragma unroll
    for (int r = 0; r < 8; r++) acc[r] = 0.0f;

    #pragma unroll
    for (int s = 0; s < 3; s++) {
        const float* __restrict__ Ws   = W + (size_t)s * K * HID;
        const float* __restrict__ xseg = xs[s] + r0 * K;
        #pragma unroll
        for (int k = 0; k < K; k++) {
            const float w0 = Ws[(size_t)k * HID + c];
            #pragma unroll
            for (int r = 0; r < 8; r++)
                acc[r] += xseg[r * K + k] * w0;
        }
    }

    const float bb = bias[c];
    float sum8 = 0.0f, mx8 = -3.402823e38f;
    #pragma unroll
    for (int r = 0; r < 8; r++) {
        const float v = leaky(acc[r] + bb);
        out[(size_t)(row0 + r0 + r) * HID + c] = v;
        sum8 += v;
        mx8 = fmaxf(mx8, v);
    }

    __shared__ float ssum[128], smx[128];
    if (r0) { ssum[c] = sum8; smx[c] = mx8; }
    __syncthreads();
    if (!r0) {
        psum[(size_t)tile * HID + c] = sum8 + ssum[c];
        pmax[(size_t)tile * HID + c] = fmaxf(mx8, smx[c]);
    }
}

// ---------------------------------------------------------------------------
// combine128: pure LDS-tiled conv GEMM (16 rows x 128 cols) + fused partial
// pool. XCD-mapped, canonical tile ids.
// ---------------------------------------------------------------------------
__global__ __launch_bounds__(256) void combine128(const float* __restrict__ X,
                                                  const float* __restrict__ Y1,
                                                  const float* __restrict__ Y2,
                                                  const float* __restrict__ W,
                                                  const float* __restrict__ bias,
                                                  float* __restrict__ out,
                                                  float* __restrict__ psum,
                                                  float* __restrict__ pmax) {
    constexpr int K = HID;
    __shared__ float xs[3][RPB * K];
    const int bid   = blockIdx.x;                // 0..511
    const int slot  = bid & 7;
    const int idx   = bid >> 3;                  // 0..63
    const int g     = slot + (idx >> 5) * 8;     // graph, 2 per XCD
    const int tile  = g * BPGR + (idx & 31);     // canonical tile id
    const int row0  = tile * RPB;
    const int tid   = threadIdx.x;

    {
        const float* s0 = X  + (size_t)row0 * K;
        const float* s1 = Y1 + (size_t)row0 * K;
        const float* s2 = Y2 + (size_t)row0 * K;
        constexpr int NV = RPB * K / 4;
        for (int i = tid; i < NV; i += 256) ((float4*)xs[0])[i] = ((const float4*)s0)[i];
        for (int i = tid; i < NV; i += 256) ((float4*)xs[1])[i] = ((const float4*)s1)[i];
        for (int i = tid; i < NV; i += 256) ((float4*)xs[2])[i] = ((const float4*)s2)[i];
    }
    __syncthreads();

    const int c  = tid & 127;
    const int r0 = (tid >> 7) * 8;

    float acc[8];
    #pragma unroll
    for (int r = 0; r < 8; r++) acc[r] = 0.0f;

    #pragma unroll
    for (int s = 0; s < 3; s++) {
        const float* __restrict__ Ws   = W + (size_t)s * K * HID;
        const float* __restrict__ xseg = xs[s] + r0 * K;
        for (int k = 0; k < K; k += 2) {
            const float w0 = Ws[(size_t)k * HID + c];
            const float w1 = Ws[(size_t)(k + 1) * HID + c];
            #pragma unroll
            for (int r = 0; r < 8; r++)
                acc[r] += xseg[r * K + k] * w0 + xseg[r * K + k + 1] * w1;
        }
    }

    const float bb = bias[c];
    float sum8 = 0.0f, mx8 = -3.402823e38f;
    #pragma unroll
    for (int r = 0; r < 8; r++) {
        const float v = leaky(acc[r] + bb);
        out[(size_t)(row0 + r0 + r) * HID + c] = v;
        sum8 += v;
        mx8 = fmaxf(mx8, v);
    }

    __shared__ float ssum[128], smx[128];
    if (r0) { ssum[c] = sum8; smx[c] = mx8; }
    __syncthreads();
    if (!r0) {
        psum[(size_t)tile * HID + c] = sum8 + ssum[c];
        pmax[(size_t)tile * HID + c] = fmaxf(mx8, smx[c]);
    }
}

// ---------------------------------------------------------------------------
// lin0: reduces all three convs' pool partials into gs[768], applies BN,
// then layer-0 GEMM. Grid = 96 blocks.
// ---------------------------------------------------------------------------
__global__ __launch_bounds__(256) void lin0_kernel(const float* __restrict__ psum1,
                                                   const float* __restrict__ pmax1,
                                                   const float* __restrict__ psum2,
                                                   const float* __restrict__ pmax2,
                                                   const float* __restrict__ psum3,
                                                   const float* __restrict__ pmax3,
                                                   const float* __restrict__ gamma,
                                                   const float* __restrict__ beta,
                                                   const float* __restrict__ mean,
                                                   const float* __restrict__ var,
                                                   const float* __restrict__ W,
                                                   const float* __restrict__ bias,
                                                   float* __restrict__ gout) {
    const int r   = blockIdx.x / 6;
    const int cc  = blockIdx.x % 6;
    const int tid = threadIdx.x;

    __shared__ float gs[H6];
    {   // task 1: conv1 (tid>>7==0) or conv2 (tid>>7==1)
        const int cv = tid >> 7;
        const int c  = tid & 127;
        const float* ps = (cv ? psum2 : psum1) + (size_t)r * BPGR * HID + c;
        const float* pm = (cv ? pmax2 : pmax1) + (size_t)r * BPGR * HID + c;
        float s = 0.0f, m = -3.402823e38f;
        #pragma unroll 8
        for (int b = 0; b < BPGR; b++) { s += ps[b * HID]; m = fmaxf(m, pm[b * HID]); }
        gs[cv * 256 + c]       = s * (1.0f / 512.0f);
        gs[cv * 256 + 128 + c] = m;
    }
    if (tid < 128) {  // task 2: conv3
        const float* ps = psum3 + (size_t)r * BPGR * HID + tid;
        const float* pm = pmax3 + (size_t)r * BPGR * HID + tid;
        float s = 0.0f, m = -3.402823e38f;
        #pragma unroll 8
        for (int b = 0; b < BPGR; b++) { s += ps[b * HID]; m = fmaxf(m, pm[b * HID]); }
        gs[512 + tid]       = s * (1.0f / 512.0f);
        gs[512 + 128 + tid] = m;
    }
    __syncthreads();
    for (int k = tid; k < H6; k += 256)
        gs[k] = (gs[k] - mean[k]) * (1.0f / sqrtf(var[k] + 1e-5f)) * gamma[k] + beta[k];
    __syncthreads();

    const int c  = cc * 128 + (tid & 127);
    const int kh = tid >> 7;
    const int kb = kh * 384;
    float a0=0.f,a1=0.f,a2=0.f,a3=0.f;
    for (int k = kb; k < kb + 384; k += 4) {
        a0 += gs[k]     * W[(size_t)(k)     * H6 + c];
        a1 += gs[k + 1] * W[(size_t)(k + 1) * H6 + c];
        a2 += gs[k + 2] * W[(size_t)(k + 2) * H6 + c];
        a3 += gs[k + 3] * W[(size_t)(k + 3) * H6 + c];
    }
    __shared__ float part[256];
    part[tid] = (a0 + a1) + (a2 + a3);
    __syncthreads();
    if (kh == 0) {
        const float v = part[tid] + part[tid + 128] + bias[c];
        gout[(size_t)r * H6 + c] = leaky(v);
    }
}

// ---------------------------------------------------------------------------
__global__ __launch_bounds__(256) void lin_kernel(const float* __restrict__ gin,
                                                  const float* __restrict__ W,
                                                  const float* __restrict__ bias,
                                                  float* __restrict__ gout) {
    const int r   = blockIdx.x / 6;
    const int cc  = blockIdx.x % 6;
    const int tid = threadIdx.x;

    __shared__ float gs[H6];
    for (int k = tid; k < H6; k += 256) gs[k] = gin[(size_t)r * H6 + k];
    __syncthreads();

    const int c  = cc * 128 + (tid & 127);
    const int kh = tid >> 7;
    const int kb = kh * 384;
    float a0=0.f,a1=0.f,a2=0.f,a3=0.f;
    for (int k = kb; k < kb + 384; k += 4) {
        a0 += gs[k]     * W[(size_t)(k)     * H6 + c];
        a1 += gs[k + 1] * W[(size_t)(k + 1) * H6 + c];
        a2 += gs[k + 2] * W[(size_t)(k + 2) * H6 + c];
        a3 += gs[k + 3] * W[(size_t)(k + 3) * H6 + c];
    }
    __shared__ float part[256];
    part[tid] = (a0 + a1) + (a2 + a3);
    __syncthreads();
    if (kh == 0) {
        const float v = part[tid] + part[tid + 128] + bias[c];
        gout[(size_t)r * H6 + c] = leaky(v);
    }
}

__global__ void out_kernel(const float* __restrict__ gin,
                           const float* __restrict__ W,
                           const float* __restrict__ bias,
                           float* __restrict__ out) {
    const int tid = threadIdx.x;
    __shared__ float part[192];
    if (tid < 192) {
        const int q  = tid >> 2;        // 0..47
        const int r  = q / 3, c = q % 3;
        const int kq = tid & 3;
        float acc = 0.0f;
        for (int k = kq * 192; k < kq * 192 + 192; k++)
            acc += gin[(size_t)r * H6 + k] * W[(size_t)k * 3 + c];
        part[tid] = acc;
    }
    __syncthreads();
    if (tid < 48) {
        const int r = tid / 3, c = tid % 3;
        out[r * 3 + c] = part[tid*4] + part[tid*4+1] + part[tid*4+2] + part[tid*4+3] + bias[c];
    }
}

// ---------------------------------------------------------------------------
extern "C" void kernel_launch(void* const* d_in, const int* in_sizes, int n_in,
                              void* d_out, int out_size, void* d_ws, size_t ws_size,
                              hipStream_t stream) {
    const float* x        = (const float*)d_in[0];
    const float* conv1_w  = (const float*)d_in[2];
    const float* conv1_b  = (const float*)d_in[3];
    const float* conv2_w  = (const float*)d_in[4];
    const float* conv2_b  = (const float*)d_in[5];
    const float* conv3_w  = (const float*)d_in[6];
    const float* conv3_b  = (const float*)d_in[7];
    const float* bn_gamma = (const float*)d_in[8];
    const float* bn_beta  = (const float*)d_in[9];
    const float* bn_mean  = (const float*)d_in[10];
    const float* bn_var   = (const float*)d_in[11];
    const float* lin_w    = (const float*)d_in[12];
    const float* lin_b    = (const float*)d_in[13];
    const float* out_w    = (const float*)d_in[14];
    const float* out_b    = (const float*)d_in[15];

    char* ws = (char*)d_ws;
    size_t off = 0;
    auto alloc = [&](size_t bytes) {
        void* p = ws + off;
        off += (bytes + 255) & ~(size_t)255;
        return p;
    };
    int*      nbr   = (int*)     alloc((size_t)N * KNN * 4);
    _Float16* Aadj  = (_Float16*)alloc((size_t)N * NPG * 2);          // 8 MB
    _Float16* Sa    = (_Float16*)alloc(2 * SPLIT_STRIDE * 2);         // 4 MB
    _Float16* Sb    = (_Float16*)alloc(2 * SPLIT_STRIDE * 2);         // 4 MB
    float*    y6a   = (float*)   alloc((size_t)N * F0 * 4);
    float*    y6b   = (float*)   alloc((size_t)N * F0 * 4);
    float*    hA    = (float*)   alloc((size_t)N * HID * 4);
    float*    hB    = (float*)   alloc((size_t)N * HID * 4);
    float*    y1    = (float*)   alloc((size_t)N * HID * 4);
    float*    y2    = (float*)   alloc((size_t)N * HID * 4);
    float*    ga    = (float*)   alloc((size_t)NG * H6 * 4);
    float*    gb    = (float*)   alloc((size_t)NG * H6 * 4);
    float*    psum1 = (float*)   alloc((size_t)(N / RPB) * HID * 4);
    float*    pmax1 = (float*)   alloc((size_t)(N / RPB) * HID * 4);
    float*    psum2 = (float*)   alloc((size_t)(N / RPB) * HID * 4);
    float*    pmax2 = (float*)   alloc((size_t)(N / RPB) * HID * 4);
    float*    psum3 = (float*)   alloc((size_t)(N / RPB) * HID * 4);
    float*    pmax3 = (float*)   alloc((size_t)(N / RPB) * HID * 4);

    knn_kernel<<<N / 4, 256, 0, stream>>>(x, nbr, Aadj);

    // conv1 (K=6)
    prop6<<<N * 8 / 256, 256, 0, stream>>>(x, nbr, y6a);
    prop6<<<N * 8 / 256, 256, 0, stream>>>(y6a, nbr, y6b);
    combine6<<<N / RPB, 256, 0, stream>>>(x, y6a, y6b, conv1_w, conv1_b, hA, psum1, pmax1);

    // conv2 (K=128): MFMA hops v3 (occupancy-fixed) + pure GEMM
    split_kernel<<<N / 64, 256, 0, stream>>>(hA, Sa);
    hop3_kernel<true ><<<1024, 128, 0, stream>>>(Aadj, Sa, y1, Sb);
    hop3_kernel<false><<<1024, 128, 0, stream>>>(Aadj, Sb, y2, nullptr);
    combine128<<<N / RPB, 256, 0, stream>>>(hA, y1, y2, conv2_w, conv2_b, hB, psum2, pmax2);

    // conv3 (K=128)
    split_kernel<<<N / 64, 256, 0, stream>>>(hB, Sa);
    hop3_kernel<true ><<<1024, 128, 0, stream>>>(Aadj, Sa, y1, Sb);
    hop3_kernel<false><<<1024, 128, 0, stream>>>(Aadj, Sb, y2, nullptr);
    combine128<<<N / RPB, 256, 0, stream>>>(hB, y1, y2, conv3_w, conv3_b, hA, psum3, pmax3);

    // head: lin0 (pool-reduce + BN fused) + 4 lin + out — 96-block structure.
    // LESSONS: (R7/R9) never shrink grid <96 blocks unless footprint trivial;
    // (R8..R18) gather-shaped reads cap ~10 TB/s from every structure tried;
    // the MFMA dense-A path streams instead — R5's 18us/hop was occupancy-
    // limited (1 blk/CU, 1 acc-chain), fixed here (4 blk/CU, 4 chains).
    lin0_kernel<<<96, 256, 0, stream>>>(psum1, pmax1, psum2, pmax2, psum3, pmax3,
                                        bn_gamma, bn_beta, bn_mean, bn_var,
                                        lin_w + 0 * H6 * H6, lin_b + 0 * H6, gb);
    lin_kernel<<<96, 256, 0, stream>>>(gb, lin_w + 1 * H6 * H6, lin_b + 1 * H6, ga);
    lin_kernel<<<96, 256, 0, stream>>>(ga, lin_w + 2 * H6 * H6, lin_b + 2 * H6, gb);
    lin_kernel<<<96, 256, 0, stream>>>(gb, lin_w + 3 * H6 * H6, lin_b + 3 * H6, ga);
    lin_kernel<<<96, 256, 0, stream>>>(ga, lin_w + 4 * H6 * H6, lin_b + 4 * H6, gb);
    out_kernel<<<1, 256, 0, stream>>>(gb, out_w, out_b, (float*)d_out);
}

// Round 20
// 248.039 us; speedup vs baseline: 1.1638x; 1.1638x over previous
//
#include <hip/hip_runtime.h>

constexpr int N    = 8192;
constexpr int NPG  = 512;   // nodes per graph
constexpr int NG   = 16;
constexpr int KNN  = 80;
constexpr int F0   = 6;
constexpr int HID  = 128;
constexpr int H6   = 768;
constexpr int RPB  = 16;    // rows per combine block
constexpr int BPGR = NPG / RPB;  // combine blocks per graph = 32

__device__ __forceinline__ float leaky(float v) { return v > 0.0f ? v : 0.01f * v; }

__device__ __forceinline__ int lanes_below(unsigned long long m) {
    return __builtin_amdgcn_mbcnt_hi((unsigned)(m >> 32),
           __builtin_amdgcn_mbcnt_lo((unsigned)m, 0));
}

// wave-sum of a per-lane count in [0,8] via 4 ballots (result uniform)
__device__ __forceinline__ int wave_count_sum(int c) {
    int total = 0;
    #pragma unroll
    for (int b = 0; b < 4; b++)
        total += (int)__popcll(__ballot((c >> b) & 1)) << b;
    return total;
}

// ---------------------------------------------------------------------------
// KNN, wave-per-target: exact rank-79 threshold via 32-step binary search on
// monotonic-mapped d2, tie-break by node order, 128-elem bitonic sort for
// output order. XCD-mapped (graph g on dispatch slot g&7).
// ---------------------------------------------------------------------------
__global__ __launch_bounds__(256) void knn_kernel(const float* __restrict__ x,
                                                  int* __restrict__ nbr) {
    const int bid   = blockIdx.x;
    const int slot  = bid & 7;
    const int idx   = bid >> 3;                 // 0..255
    const int g     = slot + 8 * (idx >> 7);    // graph, 2 per XCD
    const int chunk = idx & 127;                // 128 chunks of 4 targets
    const int tid  = threadIdx.x;
    const int lane = tid & 63;
    const int wv   = tid >> 6;
    const int base = g << 9;
    const int tl   = chunk * 4 + wv;
    const int t    = base + tl;

    __shared__ float px[512], py[512], pz[512], pw[512];
    __shared__ unsigned long long skey[4 * 128];

    for (int j = tid; j < 512; j += 256) {
        const float* row = x + (size_t)(base + j) * F0;
        const float2 ra = *(const float2*)(row);
        const float2 rb = *(const float2*)(row + 2);
        px[j] = ra.x; py[j] = ra.y; pz[j] = rb.x; pw[j] = rb.y;
    }
    __syncthreads();

    const float tx = px[tl], ty = py[tl], tz = pz[tl], tw = pw[tl];
    const float sqt = tx*tx + ty*ty + tz*tz + tw*tw;

    unsigned d2m[8];
    #pragma unroll
    for (int j = 0; j < 8; j++) {
        const int node = j * 64 + lane;
        const float jx = px[node], jy = py[node], jz = pz[node], jw = pw[node];
        const float sqj = jx*jx + jy*jy + jz*jz + jw*jw;
        const float dot = tx*jx + ty*jy + tz*jz + tw*jw;
        const float d2  = sqt + sqj - 2.0f * dot;
        unsigned u = __float_as_uint(d2);
        u = (u & 0x80000000u) ? ~u : (u | 0x80000000u);   // monotonic map
        d2m[j] = (node == tl) ? 0xFFFFFFFFu : u;          // exclude self
    }

    unsigned V = 0;
    for (int b = 31; b >= 0; --b) {
        const unsigned test = V | (1u << b);
        int c = 0;
        #pragma unroll
        for (int j = 0; j < 8; j++) c += (d2m[j] < test) ? 1 : 0;
        if (wave_count_sum(c) < KNN) V = test;
    }

    int c = 0;
    #pragma unroll
    for (int j = 0; j < 8; j++) c += (d2m[j] < V) ? 1 : 0;
    const int n_lt = wave_count_sum(c);
    const int need = KNN - n_lt;

    const int woff = wv * 128;
    int cnt_total = 0, taken = 0;
    #pragma unroll
    for (int j = 0; j < 8; j++) {
        const bool lt = d2m[j] < V;
        const bool eq = d2m[j] == V;
        const unsigned long long meq = __ballot(eq);
        const bool sel = lt || (eq && (taken + lanes_below(meq)) < need);
        taken += (int)__popcll(meq);
        const unsigned long long msel = __ballot(sel);
        if (sel) {
            const int pos = cnt_total + lanes_below(msel);
            skey[woff + pos] = ((unsigned long long)d2m[j] << 32)
                             | (unsigned)(base + j * 64 + lane);
        }
        cnt_total += (int)__popcll(msel);
    }
    for (int i = KNN + lane; i < 128; i += 64) skey[woff + i] = ~0ULL;
    __syncthreads();

    for (int kk = 2; kk <= 128; kk <<= 1) {
        for (int jj = kk >> 1; jj >= 1; jj >>= 1) {
            const int i  = ((lane & ~(jj - 1)) << 1) | (lane & (jj - 1));
            const int ix = i | jj;
            const unsigned long long a = skey[woff + i];
            const unsigned long long b = skey[woff + ix];
            const bool up = ((i & kk) == 0);
            if ((a > b) == up) { skey[woff + i] = b; skey[woff + ix] = a; }
            __syncthreads();
        }
    }

    if (lane < KNN)      nbr[t * KNN + lane]      = (int)(unsigned)skey[woff + lane];
    if (lane + 64 < KNN) nbr[t * KNN + lane + 64] = (int)(unsigned)skey[woff + lane + 64];
}

// ---------------------------------------------------------------------------
// prop6: 8 lanes per node, 10 neighbors each, shuffle-reduce. XCD-mapped.
// ---------------------------------------------------------------------------
__global__ __launch_bounds__(256) void prop6(const float* __restrict__ hin,
                                             const int* __restrict__ nbr,
                                             float* __restrict__ hout) {
    const int bid   = blockIdx.x;
    const int slot  = bid & 7;
    const int idx   = bid >> 3;                 // 0..31
    const int g     = slot + 8 * (idx >> 4);    // graph
    const int chunk = idx & 15;                 // 16 chunks of 32 nodes
    const int t     = (g << 9) + chunk * 32 + (threadIdx.x >> 3);
    const int sl    = threadIdx.x & 7;
    const int* nb   = nbr + t * KNN + sl * 10;

    float a[F0] = {0.f, 0.f, 0.f, 0.f, 0.f, 0.f};
    #pragma unroll
    for (int j = 0; j < 10; j++) {
        const float* r = hin + (size_t)nb[j] * F0;
        #pragma unroll
        for (int f = 0; f < F0; f++) a[f] += r[f];
    }
    #pragma unroll
    for (int off = 1; off < 8; off <<= 1)
        #pragma unroll
        for (int f = 0; f < F0; f++) a[f] += __shfl_xor(a[f], off);

    if (sl == 0) {
        const float inv = 1.0f / 80.0f;
        float* o = hout + (size_t)t * F0;
        #pragma unroll
        for (int f = 0; f < F0; f++) o[f] = a[f] * inv;
    }
}

// ---------------------------------------------------------------------------
// prop128: Y[t] = (1/80)*sum H[nbr]. 256-thread blocks (8 targets), grid
// 1024, XCD-mapped.
// ---------------------------------------------------------------------------
__global__ __launch_bounds__(256) void prop128(const float* __restrict__ hin,
                                               const int* __restrict__ nbr,
                                               float* __restrict__ hout) {
    const int bid   = blockIdx.x;
    const int slot  = bid & 7;
    const int g     = slot + (bid >> 9) * 8;     // graph (16 total, 2 per XCD)
    const int chunk = (bid >> 3) & 63;           // 64 chunks of 8 targets
    const int lane  = threadIdx.x & 31;
    const int t     = (g << 9) + chunk * 8 + (threadIdx.x >> 5);
    const int* nb   = nbr + t * KNN;
    float a0=0.f,a1=0.f,a2=0.f,a3=0.f;
    for (int i = 0; i < KNN; i += 16) {
        const int4 sA = *(const int4*)(nb + i);
        const int4 sB = *(const int4*)(nb + i + 4);
        const int4 sC = *(const int4*)(nb + i + 8);
        const int4 sD = *(const int4*)(nb + i + 12);
        const int idx[16] = {sA.x,sA.y,sA.z,sA.w, sB.x,sB.y,sB.z,sB.w,
                             sC.x,sC.y,sC.z,sC.w, sD.x,sD.y,sD.z,sD.w};
        float4 v[16];
        #pragma unroll
        for (int q = 0; q < 16; q++)
            v[q] = *(const float4*)(hin + (size_t)idx[q] * HID + lane * 4);
        #pragma unroll
        for (int q = 0; q < 16; q += 4) {
            a0 += (v[q].x + v[q+1].x) + (v[q+2].x + v[q+3].x);
            a1 += (v[q].y + v[q+1].y) + (v[q+2].y + v[q+3].y);
            a2 += (v[q].z + v[q+1].z) + (v[q+2].z + v[q+3].z);
            a3 += (v[q].w + v[q+1].w) + (v[q+2].w + v[q+3].w);
        }
    }
    const float inv = 1.0f / 80.0f;
    float4 r; r.x=a0*inv; r.y=a1*inv; r.z=a2*inv; r.w=a3*inv;
    *(float4*)(hout + (size_t)t * HID + lane * 4) = r;
}

// ---------------------------------------------------------------------------
// combine6: LDS-tiled GEMM for conv1 (K=6) + fused partial pool. XCD-mapped.
// ---------------------------------------------------------------------------
__global__ __launch_bounds__(256) void combine6(const float* __restrict__ X,
                                                const float* __restrict__ Y1,
                                                const float* __restrict__ Y2,
                                                const float* __restrict__ W,
                                                const float* __restrict__ bias,
                                                float* __restrict__ out,
                                                float* __restrict__ psum,
                                                float* __restrict__ pmax) {
    constexpr int K = F0;
    __shared__ float xs[3][RPB * K];
    const int bid   = blockIdx.x;               // 0..511
    const int slot  = bid & 7;
    const int idx   = bid >> 3;                 // 0..63
    const int g     = slot + 8 * (idx >> 5);
    const int tile  = g * BPGR + (idx & 31);    // canonical tile id
    const int row0  = tile * RPB;
    const int tid   = threadIdx.x;

    for (int i = tid; i < RPB * K; i += 256) xs[0][i] = X [(size_t)row0 * K + i];
    for (int i = tid; i < RPB * K; i += 256) xs[1][i] = Y1[(size_t)row0 * K + i];
    for (int i = tid; i < RPB * K; i += 256) xs[2][i] = Y2[(size_t)row0 * K + i];
    __syncthreads();

    const int c  = tid & 127;
    const int r0 = (tid >> 7) * 8;

    float acc[8];
    #pragma unroll
    for (int r = 0; r < 8; r++) acc[r] = 0.0f;

    #pragma unroll
    for (int s = 0; s < 3; s++) {
        const float* __restrict__ Ws   = W + (size_t)s * K * HID;
        const float* __restrict__ xseg = xs[s] + r0 * K;
        #pragma unroll
        for (int k = 0; k < K; k++) {
            const float w0 = Ws[(size_t)k * HID + c];
            #pragma unroll
            for (int r = 0; r < 8; r++)
                acc[r] += xseg[r * K + k] * w0;
        }
    }

    const float bb = bias[c];
    float sum8 = 0.0f, mx8 = -3.402823e38f;
    #pragma unroll
    for (int r = 0; r < 8; r++) {
        const float v = leaky(acc[r] + bb);
        out[(size_t)(row0 + r0 + r) * HID + c] = v;
        sum8 += v;
        mx8 = fmaxf(mx8, v);
    }

    __shared__ float ssum[128], smx[128];
    if (r0) { ssum[c] = sum8; smx[c] = mx8; }
    __syncthreads();
    if (!r0) {
        psum[(size_t)tile * HID + c] = sum8 + ssum[c];
        pmax[(size_t)tile * HID + c] = fmaxf(mx8, smx[c]);
    }
}

// ---------------------------------------------------------------------------
// combine128f: hop2 gather fused into conv GEMM (best-known config, RPB=16).
// XCD-mapped; psum/pmax indexed by canonical tile id.
// ---------------------------------------------------------------------------
__global__ __launch_bounds__(256) void combine128f(const float* __restrict__ X,
                                                   const float* __restrict__ Y1,
                                                   const int* __restrict__ nbr,
                                                   const float* __restrict__ W,
                                                   const float* __restrict__ bias,
                                                   float* __restrict__ out,
                                                   float* __restrict__ psum,
                                                   float* __restrict__ pmax) {
    constexpr int K = HID;
    __shared__ float xs[3][RPB * K];
    const int bid   = blockIdx.x;                // 0..511
    const int slot  = bid & 7;
    const int idx   = bid >> 3;                  // 0..63
    const int g     = slot + (idx >> 5) * 8;     // graph, 2 per XCD
    const int chunk = idx & 31;
    const int tile  = g * BPGR + chunk;          // canonical tile id
    const int row0  = tile * RPB;
    const int tid   = threadIdx.x;

    {   // stage X and Y1 tiles
        const float* s0 = X  + (size_t)row0 * K;
        const float* s1 = Y1 + (size_t)row0 * K;
        constexpr int NV = RPB * K / 4;
        for (int i = tid; i < NV; i += 256) ((float4*)xs[0])[i] = ((const float4*)s0)[i];
        for (int i = tid; i < NV; i += 256) ((float4*)xs[1])[i] = ((const float4*)s1)[i];
    }
    {   // gather Y2 tile: 8 targets in flight x 2 iters, 32 lanes = 128 cols
        const int lane = tid & 31;
        const int w8   = tid >> 5;               // 0..7
        const float inv = 1.0f / 80.0f;
        #pragma unroll
        for (int rr = 0; rr < 2; rr++) {
            const int r = w8 + rr * 8;
            const int* nb = nbr + (size_t)(row0 + r) * KNN;
            float a0=0.f,a1=0.f,a2=0.f,a3=0.f;
            for (int i = 0; i < KNN; i += 16) {
                const int4 sA = *(const int4*)(nb + i);
                const int4 sB = *(const int4*)(nb + i + 4);
                const int4 sC = *(const int4*)(nb + i + 8);
                const int4 sD = *(const int4*)(nb + i + 12);
                const int ix[16] = {sA.x,sA.y,sA.z,sA.w, sB.x,sB.y,sB.z,sB.w,
                                    sC.x,sC.y,sC.z,sC.w, sD.x,sD.y,sD.z,sD.w};
                float4 v[16];
                #pragma unroll
                for (int q = 0; q < 16; q++)
                    v[q] = *(const float4*)(Y1 + (size_t)ix[q] * HID + lane * 4);
                #pragma unroll
                for (int q = 0; q < 16; q += 4) {
                    a0 += (v[q].x + v[q+1].x) + (v[q+2].x + v[q+3].x);
                    a1 += (v[q].y + v[q+1].y) + (v[q+2].y + v[q+3].y);
                    a2 += (v[q].z + v[q+1].z) + (v[q+2].z + v[q+3].z);
                    a3 += (v[q].w + v[q+1].w) + (v[q+2].w + v[q+3].w);
                }
            }
            float4 o; o.x=a0*inv; o.y=a1*inv; o.z=a2*inv; o.w=a3*inv;
            *(float4*)&xs[2][r * K + lane * 4] = o;
        }
    }
    __syncthreads();

    const int c  = tid & 127;
    const int r0 = (tid >> 7) * 8;

    float acc[8];
    #pragma unroll
    for (int r = 0; r < 8; r++) acc[r] = 0.0f;

    #pragma unroll
    for (int s = 0; s < 3; s++) {
        const float* __restrict__ Ws   = W + (size_t)s * K * HID;
        const float* __restrict__ xseg = xs[s] + r0 * K;
        for (int k = 0; k < K; k += 2) {
            const float w0 = Ws[(size_t)k * HID + c];
            const float w1 = Ws[(size_t)(k + 1) * HID + c];
            #pragma unroll
            for (int r = 0; r < 8; r++)
                acc[r] += xseg[r * K + k] * w0 + xseg[r * K + k + 1] * w1;
        }
    }

    const float bb = bias[c];
    float sum8 = 0.0f, mx8 = -3.402823e38f;
    #pragma unroll
    for (int r = 0; r < 8; r++) {
        const float v = leaky(acc[r] + bb);
        out[(size_t)(row0 + r0 + r) * HID + c] = v;
        sum8 += v;
        mx8 = fmaxf(mx8, v);
    }

    __shared__ float ssum[128], smx[128];
    if (r0) { ssum[c] = sum8; smx[c] = mx8; }
    __syncthreads();
    if (!r0) {
        psum[(size_t)tile * HID + c] = sum8 + ssum[c];
        pmax[(size_t)tile * HID + c] = fmaxf(mx8, smx[c]);
    }
}

// ---------------------------------------------------------------------------
// lin0: reduces all three convs' pool partials into gs[768], applies BN,
// then layer-0 GEMM. Grid = 16 rows x 6 col-chunks = 96 blocks.
// ---------------------------------------------------------------------------
__global__ __launch_bounds__(256) void lin0_kernel(const float* __restrict__ psum1,
                                                   const float* __restrict__ pmax1,
                                                   const float* __restrict__ psum2,
                                                   const float* __restrict__ pmax2,
                                                   const float* __restrict__ psum3,
                                                   const float* __restrict__ pmax3,
                                                   const float* __restrict__ gamma,
                                                   const float* __restrict__ beta,
                                                   const float* __restrict__ mean,
                                                   const float* __restrict__ var,
                                                   const float* __restrict__ W,
                                                   const float* __restrict__ bias,
                                                   float* __restrict__ gout) {
    const int r   = blockIdx.x / 6;
    const int cc  = blockIdx.x % 6;
    const int tid = threadIdx.x;

    __shared__ float gs[H6];
    {   // task 1: conv1 (tid>>7==0) or conv2 (tid>>7==1)
        const int cv = tid >> 7;
        const int c  = tid & 127;
        const float* ps = (cv ? psum2 : psum1) + (size_t)r * BPGR * HID + c;
        const float* pm = (cv ? pmax2 : pmax1) + (size_t)r * BPGR * HID + c;
        float s = 0.0f, m = -3.402823e38f;
        #pragma unroll 8
        for (int b = 0; b < BPGR; b++) { s += ps[b * HID]; m = fmaxf(m, pm[b * HID]); }
        gs[cv * 256 + c]       = s * (1.0f / 512.0f);
        gs[cv * 256 + 128 + c] = m;
    }
    if (tid < 128) {  // task 2: conv3
        const float* ps = psum3 + (size_t)r * BPGR * HID + tid;
        const float* pm = pmax3 + (size_t)r * BPGR * HID + tid;
        float s = 0.0f, m = -3.402823e38f;
        #pragma unroll 8
        for (int b = 0; b < BPGR; b++) { s += ps[b * HID]; m = fmaxf(m, pm[b * HID]); }
        gs[512 + tid]       = s * (1.0f / 512.0f);
        gs[512 + 128 + tid] = m;
    }
    __syncthreads();
    for (int k = tid; k < H6; k += 256)
        gs[k] = (gs[k] - mean[k]) * (1.0f / sqrtf(var[k] + 1e-5f)) * gamma[k] + beta[k];
    __syncthreads();

    const int c  = cc * 128 + (tid & 127);
    const int kh = tid >> 7;
    const int kb = kh * 384;
    float a0=0.f,a1=0.f,a2=0.f,a3=0.f;
    for (int k = kb; k < kb + 384; k += 4) {
        a0 += gs[k]     * W[(size_t)(k)     * H6 + c];
        a1 += gs[k + 1] * W[(size_t)(k + 1) * H6 + c];
        a2 += gs[k + 2] * W[(size_t)(k + 2) * H6 + c];
        a3 += gs[k + 3] * W[(size_t)(k + 3) * H6 + c];
    }
    __shared__ float part[256];
    part[tid] = (a0 + a1) + (a2 + a3);
    __syncthreads();
    if (kh == 0) {
        const float v = part[tid] + part[tid + 128] + bias[c];
        gout[(size_t)r * H6 + c] = leaky(v);
    }
}

// ---------------------------------------------------------------------------
__global__ __launch_bounds__(256) void lin_kernel(const float* __restrict__ gin,
                                                  const float* __restrict__ W,
                                                  const float* __restrict__ bias,
                                                  float* __restrict__ gout) {
    const int r   = blockIdx.x / 6;
    const int cc  = blockIdx.x % 6;
    const int tid = threadIdx.x;

    __shared__ float gs[H6];
    for (int k = tid; k < H6; k += 256) gs[k] = gin[(size_t)r * H6 + k];
    __syncthreads();

    const int c  = cc * 128 + (tid & 127);
    const int kh = tid >> 7;
    const int kb = kh * 384;
    float a0=0.f,a1=0.f,a2=0.f,a3=0.f;
    for (int k = kb; k < kb + 384; k += 4) {
        a0 += gs[k]     * W[(size_t)(k)     * H6 + c];
        a1 += gs[k + 1] * W[(size_t)(k + 1) * H6 + c];
        a2 += gs[k + 2] * W[(size_t)(k + 2) * H6 + c];
        a3 += gs[k + 3] * W[(size_t)(k + 3) * H6 + c];
    }
    __shared__ float part[256];
    part[tid] = (a0 + a1) + (a2 + a3);
    __syncthreads();
    if (kh == 0) {
        const float v = part[tid] + part[tid + 128] + bias[c];
        gout[(size_t)r * H6 + c] = leaky(v);
    }
}

__global__ void out_kernel(const float* __restrict__ gin,
                           const float* __restrict__ W,
                           const float* __restrict__ bias,
                           float* __restrict__ out) {
    const int tid = threadIdx.x;
    __shared__ float part[192];
    if (tid < 192) {
        const int q  = tid >> 2;        // 0..47
        const int r  = q / 3, c = q % 3;
        const int kq = tid & 3;
        float acc = 0.0f;
        for (int k = kq * 192; k < kq * 192 + 192; k++)
            acc += gin[(size_t)r * H6 + k] * W[(size_t)k * 3 + c];
        part[tid] = acc;
    }
    __syncthreads();
    if (tid < 48) {
        const int r = tid / 3, c = tid % 3;
        out[r * 3 + c] = part[tid*4] + part[tid*4+1] + part[tid*4+2] + part[tid*4+3] + bias[c];
    }
}

// ---------------------------------------------------------------------------
extern "C" void kernel_launch(void* const* d_in, const int* in_sizes, int n_in,
                              void* d_out, int out_size, void* d_ws, size_t ws_size,
                              hipStream_t stream) {
    const float* x        = (const float*)d_in[0];
    const float* conv1_w  = (const float*)d_in[2];
    const float* conv1_b  = (const float*)d_in[3];
    const float* conv2_w  = (const float*)d_in[4];
    const float* conv2_b  = (const float*)d_in[5];
    const float* conv3_w  = (const float*)d_in[6];
    const float* conv3_b  = (const float*)d_in[7];
    const float* bn_gamma = (const float*)d_in[8];
    const float* bn_beta  = (const float*)d_in[9];
    const float* bn_mean  = (const float*)d_in[10];
    const float* bn_var   = (const float*)d_in[11];
    const float* lin_w    = (const float*)d_in[12];
    const float* lin_b    = (const float*)d_in[13];
    const float* out_w    = (const float*)d_in[14];
    const float* out_b    = (const float*)d_in[15];

    char* ws = (char*)d_ws;
    size_t off = 0;
    auto alloc = [&](size_t bytes) {
        void* p = ws + off;
        off += (bytes + 255) & ~(size_t)255;
        return p;
    };
    int*   nbr   = (int*)  alloc((size_t)N * KNN * 4);
    float* y6a   = (float*)alloc((size_t)N * F0 * 4);
    float* y6b   = (float*)alloc((size_t)N * F0 * 4);
    float* hA    = (float*)alloc((size_t)N * HID * 4);
    float* hB    = (float*)alloc((size_t)N * HID * 4);
    float* y1    = (float*)alloc((size_t)N * HID * 4);
    float* ga    = (float*)alloc((size_t)NG * H6 * 4);
    float* gb    = (float*)alloc((size_t)NG * H6 * 4);
    float* psum1 = (float*)alloc((size_t)(N / RPB) * HID * 4);
    float* pmax1 = (float*)alloc((size_t)(N / RPB) * HID * 4);
    float* psum2 = (float*)alloc((size_t)(N / RPB) * HID * 4);
    float* pmax2 = (float*)alloc((size_t)(N / RPB) * HID * 4);
    float* psum3 = (float*)alloc((size_t)(N / RPB) * HID * 4);
    float* pmax3 = (float*)alloc((size_t)(N / RPB) * HID * 4);

    knn_kernel<<<N / 4, 256, 0, stream>>>(x, nbr);

    // conv1 (K=6)
    prop6<<<N * 8 / 256, 256, 0, stream>>>(x, nbr, y6a);
    prop6<<<N * 8 / 256, 256, 0, stream>>>(y6a, nbr, y6b);
    combine6<<<N / RPB, 256, 0, stream>>>(x, y6a, y6b, conv1_w, conv1_b, hA, psum1, pmax1);

    // conv2 (K=128): hop1 then fused hop2+GEMM, all on graph's home XCD
    prop128<<<N / 8, 256, 0, stream>>>(hA, nbr, y1);
    combine128f<<<N / RPB, 256, 0, stream>>>(hA, y1, nbr, conv2_w, conv2_b, hB, psum2, pmax2);

    // conv3 (K=128)
    prop128<<<N / 8, 256, 0, stream>>>(hB, nbr, y1);
    combine128f<<<N / RPB, 256, 0, stream>>>(hB, y1, nbr, conv3_w, conv3_b, hA, psum3, pmax3);

    // head: lin0 (pool-reduce + BN fused) + 4 lin + out — 96-block structure.
    // FINAL STATE (R19): best-known config at ~248 us. Gather-shaped reads
    // cap at ~10 TB/s effective on this chip from every structure tried
    // (global/LDS-AoS/LDS-SoA/TLP/XCD/dense-sweep/spatial-perm/MFMA-dense-A);
    // the ~130 us of gather phases is at that structural wall.
    lin0_kernel<<<96, 256, 0, stream>>>(psum1, pmax1, psum2, pmax2, psum3, pmax3,
                                        bn_gamma, bn_beta, bn_mean, bn_var,
                                        lin_w + 0 * H6 * H6, lin_b + 0 * H6, gb);
    lin_kernel<<<96, 256, 0, stream>>>(gb, lin_w + 1 * H6 * H6, lin_b + 1 * H6, ga);
    lin_kernel<<<96, 256, 0, stream>>>(ga, lin_w + 2 * H6 * H6, lin_b + 2 * H6, gb);
    lin_kernel<<<96, 256, 0, stream>>>(gb, lin_w + 3 * H6 * H6, lin_b + 3 * H6, ga);
    lin_kernel<<<96, 256, 0, stream>>>(ga, lin_w + 4 * H6 * H6, lin_b + 4 * H6, gb);
    out_kernel<<<1, 256, 0, stream>>>(gb, out_w, out_b, (float*)d_out);
}